// Round 14
// baseline (229.719 us; speedup 1.0000x reference)
//
#include <hip/hip_runtime.h>
#include <hip/hip_fp16.h>

// ---------------------------------------------------------------------------
// GCN 2-layer forward:  out = log_softmax( A_hat * relu(A_hat * (x W1) + b1) W2 + b2 )
// A_hat = D^-1/2 (A + I) D^-1/2, deg on dst. Edge index arrives as int32.
//
// R20: 8 nodes per wave (R19's confirmed lever pushed further). Eighth-wave
// (8 lanes) owns one node:
//   agg1: fp8 row 128B = 8 lanes x 16B (uint4); acc[16]/lane; no reduce.
//   agg2: fp8 row  64B = 8 lanes x  8B (uint2); acc[8]/lane; softmax over
//         8 lanes (3 shfl).
// Finished eighths gather the L1-hot self row, cndmask'd to zero.
// Everything else (fixed-capacity CSR, 64-blk swizzle, MFMA GEMMs w/ fp8
// out, P2_I=4 partition) unchanged from R19.
// ---------------------------------------------------------------------------

#define BSHIFT 9
#define BSIZE  512            // nodes per bucket; NB = ceil(N/512) = 196 < 256
#define CAPSHIFT 14           // 16384 edge slots per bucket (mean fill ~8.2K)
#define P2_T   1024
#define P2_I   4              // edges staged per thread in partition pass

using half8  = __attribute__((ext_vector_type(8))) _Float16;
using f32x4  = __attribute__((ext_vector_type(4))) float;

__device__ __forceinline__ unsigned char f32_to_fp8(float v) {
    int p = __builtin_amdgcn_cvt_pk_fp8_f32(v, v, 0, false);
    return (unsigned char)(p & 0xff);
}

// accumulate 4 fp8 (one dword) into acc[0..3]
__device__ __forceinline__ void fp8x4_acc(unsigned int v, float* acc) {
    auto f0 = __builtin_amdgcn_cvt_pk_f32_fp8((int)v, false);
    auto f1 = __builtin_amdgcn_cvt_pk_f32_fp8((int)v, true);
    acc[0] += f0[0]; acc[1] += f0[1]; acc[2] += f1[0]; acc[3] += f1[1];
}

// --- partition edges into fixed-capacity dst-buckets, packed src|dstLocal ---
__global__ __launch_bounds__(1024) void partition_kernel(const int* __restrict__ src,
                                                         const int* __restrict__ dst,
                                                         unsigned int* __restrict__ bucket_fill,
                                                         unsigned int* __restrict__ ebuf,
                                                         int E, int NB) {
    __shared__ unsigned int hist[256];
    __shared__ unsigned int cur[256];
    int t = threadIdx.x;
    if (t < 256) hist[t] = 0u;
    __syncthreads();
    size_t base = (size_t)blockIdx.x * (P2_T * P2_I);
    int sv[P2_I], dv[P2_I];
#pragma unroll
    for (int i = 0; i < P2_I; ++i) {
        size_t idx = base + (size_t)i * P2_T + t;
        if (idx < (size_t)E) {
            sv[i] = src[idx];
            dv[i] = dst[idx];
            atomicAdd(&hist[dv[i] >> BSHIFT], 1u);
        } else dv[i] = -1;
    }
    __syncthreads();
    if (t < NB && hist[t] > 0u)
        cur[t] = ((unsigned int)t << CAPSHIFT) + atomicAdd(&bucket_fill[t], hist[t]);
    __syncthreads();
#pragma unroll
    for (int i = 0; i < P2_I; ++i) {
        if (dv[i] >= 0) {
            int b = dv[i] >> BSHIFT;
            unsigned int pos = atomicAdd(&cur[b], 1u);
            ebuf[pos] = (unsigned int)sv[i] | ((unsigned int)(dv[i] & (BSIZE - 1)) << 17);
        }
    }
}

// --- per-bucket deg/dinv/rowptr in LDS + scatter; cursor=rowend ------------
__global__ __launch_bounds__(256) void bucket_scatter2_kernel(const unsigned int* __restrict__ ebuf,
                                                              const unsigned int* __restrict__ bfill,
                                                              unsigned int* __restrict__ cursor,
                                                              unsigned int* __restrict__ deg,
                                                              float* __restrict__ dinv,
                                                              int* __restrict__ col, int N) {
    __shared__ unsigned int ldeg[BSIZE];
    __shared__ unsigned int lcur[BSIZE];
    __shared__ unsigned int part[256];
    int b = blockIdx.x, t = threadIdx.x;
    int node0 = b << BSHIFT;
    int nn = min(BSIZE, N - node0);
    ldeg[t] = 0u;
    ldeg[t + 256] = 0u;
    __syncthreads();
    unsigned int e0 = (unsigned int)b << CAPSHIFT;
    unsigned int e1 = e0 + bfill[b];
    for (unsigned int e = e0 + t; e < e1; e += 256)
        atomicAdd(&ldeg[ebuf[e] >> 17], 1u);
    __syncthreads();
    unsigned int a0 = ldeg[2 * t], a1 = ldeg[2 * t + 1];
    part[t] = a0 + a1;
    __syncthreads();
    for (int off = 1; off < 256; off <<= 1) {
        unsigned int u = part[t];
        if (t >= off) u += part[t - off];
        __syncthreads();
        part[t] = u;
        __syncthreads();
    }
    unsigned int ex = part[t] - (a0 + a1);
    lcur[2 * t]     = e0 + ex;
    lcur[2 * t + 1] = e0 + ex + a0;
    __syncthreads();
    for (unsigned int e = e0 + t; e < e1; e += 256) {
        unsigned int p = ebuf[e];
        unsigned int pos = atomicAdd(&lcur[p >> 17], 1u);
        col[pos] = (int)(p & 0x1FFFFu);
    }
    __syncthreads();
    for (int i = t; i < nn; i += 256) {
        unsigned int d = ldeg[i];
        deg[node0 + i] = d;
        dinv[node0 + i] = rsqrtf((float)(d + 1u));
        cursor[node0 + i] = lcur[i];
    }
}

// --- swizzle W1 (128x128) and W2 (128x64) into MFMA B-fragment order -------
__global__ __launch_bounds__(256) void swizzle_w_kernel(const float* __restrict__ W1,
                                                        const float* __restrict__ W2,
                                                        __half* __restrict__ w1s,
                                                        __half* __restrict__ w2s) {
    int t = blockIdx.x * 256 + threadIdx.x;
    int stride = gridDim.x * 256;
    for (int i = t; i < 8 * 4 * 64 * 8; i += stride) {   // W1: 8 col-tiles
        int j = i & 7, l = (i >> 3) & 63, s = (i >> 9) & 3, c = i >> 11;
        int k = ((l >> 4) * 8) + j + 32 * s;
        int nn = 16 * c + (l & 15);
        w1s[i] = __float2half(W1[k * 128 + nn]);
    }
    for (int i = t; i < 4 * 4 * 64 * 8; i += stride) {   // W2: 4 col-tiles
        int j = i & 7, l = (i >> 3) & 63, s = (i >> 9) & 3, c = i >> 11;
        int k = ((l >> 4) * 8) + j + 32 * s;
        int nn = 16 * c + (l & 15);
        w2s[i] = __float2half(W2[k * 64 + nn]);
    }
}

// --- GEMM1 (MFMA): Y8[r,128] = fp8( dinv[r] * (X[r,128] @ W1) ), X fp32 ----
__global__ __launch_bounds__(256) void gemm1_mfma_kernel(const float* __restrict__ X,
                                                         const __half* __restrict__ w1s,
                                                         const float* __restrict__ dinv,
                                                         unsigned char* __restrict__ Y8, int n) {
    int t = threadIdx.x;
    int wave = t >> 6, lane = t & 63;
    int quad = lane >> 4, m = lane & 15;
    int rowbase = blockIdx.x * 64 + wave * 16;
    int arow = rowbase + m;
    bool aok = arow < n;
    const float* xr = X + (size_t)arow * 128 + quad * 8;

    half8 afrag[4];
#pragma unroll
    for (int s = 0; s < 4; ++s) {
        float4 p0 = make_float4(0.f, 0.f, 0.f, 0.f), p1 = p0;
        if (aok) {
            p0 = *(const float4*)(xr + s * 32);
            p1 = *(const float4*)(xr + s * 32 + 4);
        }
        afrag[s][0] = (_Float16)p0.x; afrag[s][1] = (_Float16)p0.y;
        afrag[s][2] = (_Float16)p0.z; afrag[s][3] = (_Float16)p0.w;
        afrag[s][4] = (_Float16)p1.x; afrag[s][5] = (_Float16)p1.y;
        afrag[s][6] = (_Float16)p1.z; afrag[s][7] = (_Float16)p1.w;
    }

    const half8* bp = (const half8*)w1s;
    f32x4 acc[8];
#pragma unroll
    for (int c = 0; c < 8; ++c) acc[c] = (f32x4){0.f, 0.f, 0.f, 0.f};
#pragma unroll
    for (int c = 0; c < 8; ++c)
#pragma unroll
        for (int s = 0; s < 4; ++s)
            acc[c] = __builtin_amdgcn_mfma_f32_16x16x32_f16(afrag[s], bp[(c * 4 + s) * 64 + lane], acc[c], 0, 0, 0);

#pragma unroll
    for (int i = 0; i < 4; ++i) {
        int row = rowbase + quad * 4 + i;
        if (row < n) {
            float w = dinv[row];
            unsigned char* yr = Y8 + (size_t)row * 128 + m;
#pragma unroll
            for (int c = 0; c < 8; ++c) yr[c * 16] = f32_to_fp8(acc[c][i] * w);
        }
    }
}

// --- GEMM2 (MFMA): Y8[r,64] = fp8( dinv[r] * (Xh[r,128] @ W2) ), X fp16 ----
__global__ __launch_bounds__(256) void gemm2_mfma_kernel(const __half* __restrict__ X,
                                                         const __half* __restrict__ w2s,
                                                         const float* __restrict__ dinv,
                                                         unsigned char* __restrict__ Y8, int n) {
    int t = threadIdx.x;
    int wave = t >> 6, lane = t & 63;
    int quad = lane >> 4, m = lane & 15;
    int rowbase = blockIdx.x * 64 + wave * 16;
    int arow = rowbase + m;
    bool aok = arow < n;
    const __half* xr = X + (size_t)arow * 128 + quad * 8;

    half8 afrag[4];
#pragma unroll
    for (int s = 0; s < 4; ++s) {
        if (aok) afrag[s] = *(const half8*)(xr + s * 32);
        else     afrag[s] = (half8){0, 0, 0, 0, 0, 0, 0, 0};
    }

    const half8* bp = (const half8*)w2s;
    f32x4 acc[4];
#pragma unroll
    for (int c = 0; c < 4; ++c) acc[c] = (f32x4){0.f, 0.f, 0.f, 0.f};
#pragma unroll
    for (int c = 0; c < 4; ++c)
#pragma unroll
        for (int s = 0; s < 4; ++s)
            acc[c] = __builtin_amdgcn_mfma_f32_16x16x32_f16(afrag[s], bp[(c * 4 + s) * 64 + lane], acc[c], 0, 0, 0);

#pragma unroll
    for (int i = 0; i < 4; ++i) {
        int row = rowbase + quad * 4 + i;
        if (row < n) {
            float w = dinv[row];
            unsigned char* yr = Y8 + (size_t)row * 64 + m;
#pragma unroll
            for (int c = 0; c < 4; ++c) yr[c * 16] = f32_to_fp8(acc[c][i] * w);
        }
    }
}

// --- pull layer 1: H[d] = relu(dinv[d]*(T'[d] + sum T'[col]) + b1), F=128 --
// R20: 8 nodes/wave. Eighth (8 lanes) owns a node; lane f holds features
// f*16..f*16+15 (16B of the 128B fp8 row, one uint4/edge). No reduce.
__global__ __launch_bounds__(256) void pull_agg1_kernel(const unsigned char* __restrict__ T8,
                                                        const int* __restrict__ col,
                                                        const unsigned int* __restrict__ cursor,
                                                        const unsigned int* __restrict__ deg,
                                                        const float* __restrict__ dinv,
                                                        const float* __restrict__ b1,
                                                        __half* __restrict__ H, int N) {
    int wid = blockIdx.x * 4 + (threadIdx.x >> 6);
    int lane = threadIdx.x & 63;
    int o = lane >> 3, f = lane & 7;
    int node = wid * 8 + o;
    bool act = node < N;
    unsigned int nodeC = (unsigned int)(act ? node : (N - 1));
    unsigned int end = cursor[nodeC];
    unsigned int e = end - deg[nodeC];
    if (!act) e = end;
    unsigned int boff = (unsigned int)f << 4;       // 16B per lane

    float acc[16];
    {   // self term
        uint4 w = *(const uint4*)(T8 + nodeC * 128u + boff);
        auto f0 = __builtin_amdgcn_cvt_pk_f32_fp8((int)w.x, false);
        auto f1 = __builtin_amdgcn_cvt_pk_f32_fp8((int)w.x, true);
        auto f2 = __builtin_amdgcn_cvt_pk_f32_fp8((int)w.y, false);
        auto f3 = __builtin_amdgcn_cvt_pk_f32_fp8((int)w.y, true);
        auto f4 = __builtin_amdgcn_cvt_pk_f32_fp8((int)w.z, false);
        auto f5 = __builtin_amdgcn_cvt_pk_f32_fp8((int)w.z, true);
        auto f6 = __builtin_amdgcn_cvt_pk_f32_fp8((int)w.w, false);
        auto f7 = __builtin_amdgcn_cvt_pk_f32_fp8((int)w.w, true);
        acc[0]  = f0[0]; acc[1]  = f0[1]; acc[2]  = f1[0]; acc[3]  = f1[1];
        acc[4]  = f2[0]; acc[5]  = f2[1]; acc[6]  = f3[0]; acc[7]  = f3[1];
        acc[8]  = f4[0]; acc[9]  = f4[1]; acc[10] = f5[0]; acc[11] = f5[1];
        acc[12] = f6[0]; acc[13] = f6[1]; acc[14] = f7[0]; acc[15] = f7[1];
    }

    while (__any(e < end)) {                        // 8 edges/eighth/iter
        unsigned int s[8];
#pragma unroll
        for (int k = 0; k < 8; ++k) s[k] = (unsigned int)col[e + k];  // eighth-uniform addr
#pragma unroll
        for (int k = 0; k < 8; ++k) {
            bool ok = (e + k) < end;
            unsigned int idx = ok ? min(s[k], (unsigned int)(N - 1)) : nodeC;
            uint4 v = *(const uint4*)(T8 + idx * 128u + boff);
            v.x = ok ? v.x : 0u;
            v.y = ok ? v.y : 0u;
            v.z = ok ? v.z : 0u;
            v.w = ok ? v.w : 0u;
            fp8x4_acc(v.x, acc);
            fp8x4_acc(v.y, acc + 4);
            fp8x4_acc(v.z, acc + 8);
            fp8x4_acc(v.w, acc + 12);
        }
        e += 8u;
    }

    if (act) {
        float dv = dinv[node];
        const float4* bp = (const float4*)b1;       // features f*16..f*16+15
        __half2 h[8];
#pragma unroll
        for (int k = 0; k < 4; ++k) {
            float4 bb = bp[4 * f + k];
            h[2 * k]     = __floats2half2_rn(fmaxf(fmaf(dv, acc[4 * k],     bb.x), 0.f),
                                             fmaxf(fmaf(dv, acc[4 * k + 1], bb.y), 0.f));
            h[2 * k + 1] = __floats2half2_rn(fmaxf(fmaf(dv, acc[4 * k + 2], bb.z), 0.f),
                                             fmaxf(fmaf(dv, acc[4 * k + 3], bb.w), 0.f));
        }
        uint4 s0, s1;
        s0.x = *(unsigned int*)&h[0]; s0.y = *(unsigned int*)&h[1];
        s0.z = *(unsigned int*)&h[2]; s0.w = *(unsigned int*)&h[3];
        s1.x = *(unsigned int*)&h[4]; s1.y = *(unsigned int*)&h[5];
        s1.z = *(unsigned int*)&h[6]; s1.w = *(unsigned int*)&h[7];
        char* hb = (char*)H + (size_t)node * 256 + f * 32;
        *(uint4*)hb = s0;
        *(uint4*)(hb + 16) = s1;
    }
}

// --- pull layer 2 + logsoftmax: out[d] = lsm(dinv[d]*sum + b2), F=64 -------
// R20: 8 nodes/wave. Eighth owns a node; lane f holds features f*8..f*8+7
// (8B of the 64B fp8 row, one uint2/edge). Softmax over 8 lanes (3 shfl).
__global__ __launch_bounds__(256) void pull_agg2_kernel(const unsigned char* __restrict__ T8,
                                                        const int* __restrict__ col,
                                                        const unsigned int* __restrict__ cursor,
                                                        const unsigned int* __restrict__ deg,
                                                        const float* __restrict__ dinv,
                                                        const float* __restrict__ b2,
                                                        float* __restrict__ OUT, int N) {
    int wid = blockIdx.x * 4 + (threadIdx.x >> 6);
    int lane = threadIdx.x & 63;
    int o = lane >> 3, f = lane & 7;
    int node = wid * 8 + o;
    bool act = node < N;
    unsigned int nodeC = (unsigned int)(act ? node : (N - 1));
    unsigned int end = cursor[nodeC];
    unsigned int e = end - deg[nodeC];
    if (!act) e = end;
    unsigned int boff = (unsigned int)f << 3;       // 8B per lane

    float acc[8];
    {   // self term
        uint2 w = *(const uint2*)(T8 + nodeC * 64u + boff);
        auto f0 = __builtin_amdgcn_cvt_pk_f32_fp8((int)w.x, false);
        auto f1 = __builtin_amdgcn_cvt_pk_f32_fp8((int)w.x, true);
        auto f2 = __builtin_amdgcn_cvt_pk_f32_fp8((int)w.y, false);
        auto f3 = __builtin_amdgcn_cvt_pk_f32_fp8((int)w.y, true);
        acc[0] = f0[0]; acc[1] = f0[1]; acc[2] = f1[0]; acc[3] = f1[1];
        acc[4] = f2[0]; acc[5] = f2[1]; acc[6] = f3[0]; acc[7] = f3[1];
    }

    while (__any(e < end)) {                        // 8 edges/eighth/iter
        unsigned int s[8];
#pragma unroll
        for (int k = 0; k < 8; ++k) s[k] = (unsigned int)col[e + k];
#pragma unroll
        for (int k = 0; k < 8; ++k) {
            bool ok = (e + k) < end;
            unsigned int idx = ok ? min(s[k], (unsigned int)(N - 1)) : nodeC;
            uint2 v = *(const uint2*)(T8 + idx * 64u + boff);
            v.x = ok ? v.x : 0u;
            v.y = ok ? v.y : 0u;
            fp8x4_acc(v.x, acc);
            fp8x4_acc(v.y, acc + 4);
        }
        e += 8u;
    }

    float dv = dinv[nodeC];
    const float4* bp = (const float4*)b2;           // features f*8..f*8+7
    float4 b0 = bp[2 * f], b1v = bp[2 * f + 1];
    float v[8];
    v[0] = fmaf(dv, acc[0], b0.x);
    v[1] = fmaf(dv, acc[1], b0.y);
    v[2] = fmaf(dv, acc[2], b0.z);
    v[3] = fmaf(dv, acc[3], b0.w);
    v[4] = fmaf(dv, acc[4], b1v.x);
    v[5] = fmaf(dv, acc[5], b1v.y);
    v[6] = fmaf(dv, acc[6], b1v.z);
    v[7] = fmaf(dv, acc[7], b1v.w);
    float m = v[0];
#pragma unroll
    for (int j = 1; j < 8; ++j) m = fmaxf(m, v[j]);
    m = fmaxf(m, __shfl_xor(m, 1));
    m = fmaxf(m, __shfl_xor(m, 2));
    m = fmaxf(m, __shfl_xor(m, 4));
    float sum = 0.f;
#pragma unroll
    for (int j = 0; j < 8; ++j) sum += __expf(v[j] - m);
    sum += __shfl_xor(sum, 1);
    sum += __shfl_xor(sum, 2);
    sum += __shfl_xor(sum, 4);
    float ls = m + logf(sum);
    if (act) {
        float* ob = OUT + (size_t)node * 64 + f * 8;
        *(float4*)ob       = make_float4(v[0] - ls, v[1] - ls, v[2] - ls, v[3] - ls);
        *(float4*)(ob + 4) = make_float4(v[4] - ls, v[5] - ls, v[6] - ls, v[7] - ls);
    }
}

extern "C" void kernel_launch(void* const* d_in, const int* in_sizes, int n_in,
                              void* d_out, int out_size, void* d_ws, size_t ws_size,
                              hipStream_t stream) {
    const float* x   = (const float*)d_in[0];
    const int*   ei  = (const int*)d_in[1];   // int32 per harness contract
    const float* W1  = (const float*)d_in[2];
    const float* b1  = (const float*)d_in[3];
    const float* W2  = (const float*)d_in[4];
    const float* b2  = (const float*)d_in[5];
    float*       out = (float*)d_out;

    const int N = in_sizes[0] / 128;      // 100000
    const int E = in_sizes[1] / 2;        // 1600000
    const int* src = ei;
    const int* dst = ei + E;
    const int NB = (N + BSIZE - 1) >> BSHIFT;   // dst buckets (196 <= 256)
    const size_t CAPTOT = (size_t)NB << CAPSHIFT;

    // workspace layout
    char* ws = (char*)d_ws;
    size_t off = 0;
    auto alloc = [&](size_t bytes) { void* p = ws + off; off = (off + bytes + 255) & ~(size_t)255; return p; };
    unsigned int* deg    = (unsigned int*)alloc((size_t)N * 4);
    float*        dinv   = (float*)alloc((size_t)N * 4);
    unsigned int* cursor = (unsigned int*)alloc((size_t)N * 4);
    unsigned int* bf     = (unsigned int*)alloc(256 * 4);       // bucket_fill
    __half*       w1s    = (__half*)alloc(128 * 128 * 2);       // swizzled W1
    __half*       w2s    = (__half*)alloc(128 * 64 * 2);        // swizzled W2
    int*          col    = (int*)alloc(CAPTOT * 4 + 256);       // CAP-strided (+overrun pad)
    unsigned char* A     = (unsigned char*)alloc((size_t)N * 128); // T1'/T2' fp8
    __half*       B      = (__half*)alloc((size_t)N * 128 * 2);    // h fp16
    unsigned int* ebuf   = (unsigned int*)alloc(CAPTOT * 4);

    // 1. CSR build: partition into fixed-capacity buckets -> per-bucket scatter
    hipMemsetAsync(bf, 0, 256 * 4, stream);
    partition_kernel<<<(E + P2_T * P2_I - 1) / (P2_T * P2_I), P2_T, 0, stream>>>(src, dst, bf, ebuf, E, NB);
    bucket_scatter2_kernel<<<NB, 256, 0, stream>>>(ebuf, bf, cursor, deg, dinv, col, N);
    // now cursor[i] == rowend(i); rowstart(i) = cursor[i] - deg[i]; dinv ready

    // 1b. swizzle weights into MFMA fragment order
    swizzle_w_kernel<<<64, 256, 0, stream>>>(W1, W2, w1s, w2s);

    // 2. T1' = fp8(dinv * (x @ W1)) [MFMA];  h = relu(dinv*(pull) + b1)
    gemm1_mfma_kernel<<<(N + 63) / 64, 256, 0, stream>>>(x, w1s, dinv, A, N);
    pull_agg1_kernel<<<(N + 31) / 32, 256, 0, stream>>>(A, col, cursor, deg, dinv, b1, B, N);

    // 3. T2' = fp8(dinv * (h @ W2)) [MFMA];  out = logsoftmax(dinv*(pull) + b2)
    gemm2_mfma_kernel<<<(N + 63) / 64, 256, 0, stream>>>(B, w2s, dinv, A, N);
    pull_agg2_kernel<<<(N + 31) / 32, 256, 0, stream>>>(A, col, cursor, deg, dinv, b2, out, N);
}

// Round 15
// 220.333 us; speedup vs baseline: 1.0426x; 1.0426x over previous
//
#include <hip/hip_runtime.h>
#include <hip/hip_fp16.h>

// ---------------------------------------------------------------------------
// GCN 2-layer forward:  out = log_softmax( A_hat * relu(A_hat * (x W1) + b1) W2 + b2 )
// A_hat = D^-1/2 (A + I) D^-1/2, deg on dst. Edge index arrives as int32.
//
// R21: CSR chain de-starved. BSIZE 512->256 (NB 196->391 blocks; scatter was
// <1 block/CU), one-entry-per-thread 256-scan (half the barriers), CAP 8192.
// swizzle_w folded into partition's last block (one launch fewer).
// Pulls: R19's quarter-wave (4 nodes/wave) exactly -- best measured (227.5).
// GEMMs: fp16 MFMA with fp8 e4m3 output, unchanged.
// ---------------------------------------------------------------------------

#define BSHIFT 8
#define BSIZE  256            // nodes per bucket; NB = ceil(N/256) = 391
#define CAPSHIFT 13           // 8192 edge slots per bucket (mean fill ~4.1K)
#define P2_T   1024
#define P2_I   4              // edges staged per thread in partition pass

using half8  = __attribute__((ext_vector_type(8))) _Float16;
using f32x4  = __attribute__((ext_vector_type(4))) float;

__device__ __forceinline__ unsigned char f32_to_fp8(float v) {
    int p = __builtin_amdgcn_cvt_pk_fp8_f32(v, v, 0, false);
    return (unsigned char)(p & 0xff);
}

// accumulate 4 fp8 (one dword) into acc[0..3]
__device__ __forceinline__ void fp8x4_acc(unsigned int v, float* acc) {
    auto f0 = __builtin_amdgcn_cvt_pk_f32_fp8((int)v, false);
    auto f1 = __builtin_amdgcn_cvt_pk_f32_fp8((int)v, true);
    acc[0] += f0[0]; acc[1] += f0[1]; acc[2] += f1[0]; acc[3] += f1[1];
}

// --- partition edges into fixed-capacity dst-buckets, packed src|dstLocal ---
// Last block does the W1/W2 swizzle instead (fold: one launch fewer).
__global__ __launch_bounds__(1024) void partition_kernel(const int* __restrict__ src,
                                                         const int* __restrict__ dst,
                                                         unsigned int* __restrict__ bucket_fill,
                                                         unsigned int* __restrict__ ebuf,
                                                         const float* __restrict__ W1,
                                                         const float* __restrict__ W2,
                                                         __half* __restrict__ w1s,
                                                         __half* __restrict__ w2s,
                                                         int E, int NB) {
    int t = threadIdx.x;
    if (blockIdx.x == gridDim.x - 1) {             // swizzle block
        for (int i = t; i < 8 * 4 * 64 * 8; i += 1024) {   // W1: 8 col-tiles
            int j = i & 7, l = (i >> 3) & 63, s = (i >> 9) & 3, c = i >> 11;
            int k = ((l >> 4) * 8) + j + 32 * s;
            int nn = 16 * c + (l & 15);
            w1s[i] = __float2half(W1[k * 128 + nn]);
        }
        for (int i = t; i < 4 * 4 * 64 * 8; i += 1024) {   // W2: 4 col-tiles
            int j = i & 7, l = (i >> 3) & 63, s = (i >> 9) & 3, c = i >> 11;
            int k = ((l >> 4) * 8) + j + 32 * s;
            int nn = 16 * c + (l & 15);
            w2s[i] = __float2half(W2[k * 64 + nn]);
        }
        return;
    }
    __shared__ unsigned int hist[512];
    __shared__ unsigned int cur[512];
    if (t < 512) hist[t] = 0u;
    __syncthreads();
    size_t base = (size_t)blockIdx.x * (P2_T * P2_I);
    int sv[P2_I], dv[P2_I];
#pragma unroll
    for (int i = 0; i < P2_I; ++i) {
        size_t idx = base + (size_t)i * P2_T + t;
        if (idx < (size_t)E) {
            sv[i] = src[idx];
            dv[i] = dst[idx];
            atomicAdd(&hist[dv[i] >> BSHIFT], 1u);
        } else dv[i] = -1;
    }
    __syncthreads();
    if (t < NB && hist[t] > 0u)
        cur[t] = ((unsigned int)t << CAPSHIFT) + atomicAdd(&bucket_fill[t], hist[t]);
    __syncthreads();
#pragma unroll
    for (int i = 0; i < P2_I; ++i) {
        if (dv[i] >= 0) {
            int b = dv[i] >> BSHIFT;
            unsigned int pos = atomicAdd(&cur[b], 1u);
            ebuf[pos] = (unsigned int)sv[i] | ((unsigned int)(dv[i] & (BSIZE - 1)) << 17);
        }
    }
}

// --- per-bucket deg/dinv/rowptr in LDS + scatter; cursor=rowend ------------
// BSIZE=256: one node per thread, single-entry 256-scan.
__global__ __launch_bounds__(256) void bucket_scatter2_kernel(const unsigned int* __restrict__ ebuf,
                                                              const unsigned int* __restrict__ bfill,
                                                              unsigned int* __restrict__ cursor,
                                                              unsigned int* __restrict__ deg,
                                                              float* __restrict__ dinv,
                                                              int* __restrict__ col, int N) {
    __shared__ unsigned int ldeg[BSIZE];
    __shared__ unsigned int lcur[BSIZE];
    __shared__ unsigned int part[256];
    int b = blockIdx.x, t = threadIdx.x;
    int node0 = b << BSHIFT;
    int nn = min(BSIZE, N - node0);
    ldeg[t] = 0u;
    __syncthreads();
    unsigned int e0 = (unsigned int)b << CAPSHIFT;
    unsigned int e1 = e0 + bfill[b];
    for (unsigned int e = e0 + t; e < e1; e += 256)
        atomicAdd(&ldeg[ebuf[e] >> 17], 1u);
    __syncthreads();
    unsigned int v = ldeg[t];
    part[t] = v;
    __syncthreads();
    for (int off = 1; off < 256; off <<= 1) {
        unsigned int u = part[t];
        if (t >= off) u += part[t - off];
        __syncthreads();
        part[t] = u;
        __syncthreads();
    }
    lcur[t] = e0 + part[t] - v;                    // exclusive prefix
    __syncthreads();
    for (unsigned int e = e0 + t; e < e1; e += 256) {
        unsigned int p = ebuf[e];
        unsigned int pos = atomicAdd(&lcur[p >> 17], 1u);
        col[pos] = (int)(p & 0x1FFFFu);
    }
    __syncthreads();
    if (t < nn) {
        unsigned int d = ldeg[t];
        deg[node0 + t] = d;
        dinv[node0 + t] = rsqrtf((float)(d + 1u));
        cursor[node0 + t] = lcur[t];
    }
}

// --- GEMM1 (MFMA): Y8[r,128] = fp8( dinv[r] * (X[r,128] @ W1) ), X fp32 ----
__global__ __launch_bounds__(256) void gemm1_mfma_kernel(const float* __restrict__ X,
                                                         const __half* __restrict__ w1s,
                                                         const float* __restrict__ dinv,
                                                         unsigned char* __restrict__ Y8, int n) {
    int t = threadIdx.x;
    int wave = t >> 6, lane = t & 63;
    int quad = lane >> 4, m = lane & 15;
    int rowbase = blockIdx.x * 64 + wave * 16;
    int arow = rowbase + m;
    bool aok = arow < n;
    const float* xr = X + (size_t)arow * 128 + quad * 8;

    half8 afrag[4];
#pragma unroll
    for (int s = 0; s < 4; ++s) {
        float4 p0 = make_float4(0.f, 0.f, 0.f, 0.f), p1 = p0;
        if (aok) {
            p0 = *(const float4*)(xr + s * 32);
            p1 = *(const float4*)(xr + s * 32 + 4);
        }
        afrag[s][0] = (_Float16)p0.x; afrag[s][1] = (_Float16)p0.y;
        afrag[s][2] = (_Float16)p0.z; afrag[s][3] = (_Float16)p0.w;
        afrag[s][4] = (_Float16)p1.x; afrag[s][5] = (_Float16)p1.y;
        afrag[s][6] = (_Float16)p1.z; afrag[s][7] = (_Float16)p1.w;
    }

    const half8* bp = (const half8*)w1s;
    f32x4 acc[8];
#pragma unroll
    for (int c = 0; c < 8; ++c) acc[c] = (f32x4){0.f, 0.f, 0.f, 0.f};
#pragma unroll
    for (int c = 0; c < 8; ++c)
#pragma unroll
        for (int s = 0; s < 4; ++s)
            acc[c] = __builtin_amdgcn_mfma_f32_16x16x32_f16(afrag[s], bp[(c * 4 + s) * 64 + lane], acc[c], 0, 0, 0);

#pragma unroll
    for (int i = 0; i < 4; ++i) {
        int row = rowbase + quad * 4 + i;
        if (row < n) {
            float w = dinv[row];
            unsigned char* yr = Y8 + (size_t)row * 128 + m;
#pragma unroll
            for (int c = 0; c < 8; ++c) yr[c * 16] = f32_to_fp8(acc[c][i] * w);
        }
    }
}

// --- GEMM2 (MFMA): Y8[r,64] = fp8( dinv[r] * (Xh[r,128] @ W2) ), X fp16 ----
__global__ __launch_bounds__(256) void gemm2_mfma_kernel(const __half* __restrict__ X,
                                                         const __half* __restrict__ w2s,
                                                         const float* __restrict__ dinv,
                                                         unsigned char* __restrict__ Y8, int n) {
    int t = threadIdx.x;
    int wave = t >> 6, lane = t & 63;
    int quad = lane >> 4, m = lane & 15;
    int rowbase = blockIdx.x * 64 + wave * 16;
    int arow = rowbase + m;
    bool aok = arow < n;
    const __half* xr = X + (size_t)arow * 128 + quad * 8;

    half8 afrag[4];
#pragma unroll
    for (int s = 0; s < 4; ++s) {
        if (aok) afrag[s] = *(const half8*)(xr + s * 32);
        else     afrag[s] = (half8){0, 0, 0, 0, 0, 0, 0, 0};
    }

    const half8* bp = (const half8*)w2s;
    f32x4 acc[4];
#pragma unroll
    for (int c = 0; c < 4; ++c) acc[c] = (f32x4){0.f, 0.f, 0.f, 0.f};
#pragma unroll
    for (int c = 0; c < 4; ++c)
#pragma unroll
        for (int s = 0; s < 4; ++s)
            acc[c] = __builtin_amdgcn_mfma_f32_16x16x32_f16(afrag[s], bp[(c * 4 + s) * 64 + lane], acc[c], 0, 0, 0);

#pragma unroll
    for (int i = 0; i < 4; ++i) {
        int row = rowbase + quad * 4 + i;
        if (row < n) {
            float w = dinv[row];
            unsigned char* yr = Y8 + (size_t)row * 64 + m;
#pragma unroll
            for (int c = 0; c < 4; ++c) yr[c * 16] = f32_to_fp8(acc[c][i] * w);
        }
    }
}

// --- pull layer 1: H[d] = relu(dinv[d]*(T'[d] + sum T'[col]) + b1), F=128 --
// R19 structure: 4 nodes/wave. Quarter (16 lanes) owns a node; lane f holds
// features f*8..f*8+7 (8B of the 128B fp8 row). No cross-lane reduce.
__global__ __launch_bounds__(256) void pull_agg1_kernel(const unsigned char* __restrict__ T8,
                                                        const int* __restrict__ col,
                                                        const unsigned int* __restrict__ cursor,
                                                        const unsigned int* __restrict__ deg,
                                                        const float* __restrict__ dinv,
                                                        const float* __restrict__ b1,
                                                        __half* __restrict__ H, int N) {
    int wid = blockIdx.x * 4 + (threadIdx.x >> 6);
    int lane = threadIdx.x & 63;
    int q = lane >> 4, f = lane & 15;
    int node = wid * 4 + q;
    bool act = node < N;
    unsigned int nodeC = (unsigned int)(act ? node : (N - 1));
    unsigned int end = cursor[nodeC];
    unsigned int e = end - deg[nodeC];
    if (!act) e = end;
    unsigned int boff = (unsigned int)f << 3;       // 8B per lane

    float acc[8];
    {   // self term
        const unsigned int* rp = (const unsigned int*)(T8 + nodeC * 128u + boff);
        unsigned int w0 = rp[0], w1 = rp[1];
        auto f0 = __builtin_amdgcn_cvt_pk_f32_fp8((int)w0, false);
        auto f1 = __builtin_amdgcn_cvt_pk_f32_fp8((int)w0, true);
        auto f2 = __builtin_amdgcn_cvt_pk_f32_fp8((int)w1, false);
        auto f3 = __builtin_amdgcn_cvt_pk_f32_fp8((int)w1, true);
        acc[0] = f0[0]; acc[1] = f0[1]; acc[2] = f1[0]; acc[3] = f1[1];
        acc[4] = f2[0]; acc[5] = f2[1]; acc[6] = f3[0]; acc[7] = f3[1];
    }

    while (__any(e < end)) {                        // 8 edges/quarter/iter
        unsigned int s[8];
#pragma unroll
        for (int k = 0; k < 8; ++k) s[k] = (unsigned int)col[e + k];  // quarter-uniform addr
#pragma unroll
        for (int k = 0; k < 8; ++k) {
            bool ok = (e + k) < end;
            unsigned int idx = ok ? min(s[k], (unsigned int)(N - 1)) : nodeC;
            const unsigned int* rp = (const unsigned int*)(T8 + idx * 128u + boff);
            unsigned int v0 = rp[0], v1 = rp[1];
            v0 = ok ? v0 : 0u;
            v1 = ok ? v1 : 0u;
            fp8x4_acc(v0, acc);
            fp8x4_acc(v1, acc + 4);
        }
        e += 8u;
    }

    if (act) {
        float dv = dinv[node];
        const float4* bp = (const float4*)b1;       // features f*8..f*8+7
        float4 ba = bp[2 * f], bb = bp[2 * f + 1];
        __half2 h0 = __floats2half2_rn(fmaxf(fmaf(dv, acc[0], ba.x), 0.f),
                                       fmaxf(fmaf(dv, acc[1], ba.y), 0.f));
        __half2 h1 = __floats2half2_rn(fmaxf(fmaf(dv, acc[2], ba.z), 0.f),
                                       fmaxf(fmaf(dv, acc[3], ba.w), 0.f));
        __half2 h2 = __floats2half2_rn(fmaxf(fmaf(dv, acc[4], bb.x), 0.f),
                                       fmaxf(fmaf(dv, acc[5], bb.y), 0.f));
        __half2 h3 = __floats2half2_rn(fmaxf(fmaf(dv, acc[6], bb.z), 0.f),
                                       fmaxf(fmaf(dv, acc[7], bb.w), 0.f));
        uint4 st;
        st.x = *(unsigned int*)&h0; st.y = *(unsigned int*)&h1;
        st.z = *(unsigned int*)&h2; st.w = *(unsigned int*)&h3;
        *(uint4*)((char*)H + (size_t)node * 256 + f * 16) = st;
    }
}

// --- pull layer 2 + logsoftmax: out[d] = lsm(dinv[d]*sum + b2), F=64 -------
// R19 structure: 4 nodes/wave. Quarter owns a node; lane f holds features
// f*4..f*4+3 (4B of the 64B fp8 row). Softmax over the 16-lane quarter.
__global__ __launch_bounds__(256) void pull_agg2_kernel(const unsigned char* __restrict__ T8,
                                                        const int* __restrict__ col,
                                                        const unsigned int* __restrict__ cursor,
                                                        const unsigned int* __restrict__ deg,
                                                        const float* __restrict__ dinv,
                                                        const float* __restrict__ b2,
                                                        float* __restrict__ OUT, int N) {
    int wid = blockIdx.x * 4 + (threadIdx.x >> 6);
    int lane = threadIdx.x & 63;
    int q = lane >> 4, f = lane & 15;
    int node = wid * 4 + q;
    bool act = node < N;
    unsigned int nodeC = (unsigned int)(act ? node : (N - 1));
    unsigned int end = cursor[nodeC];
    unsigned int e = end - deg[nodeC];
    if (!act) e = end;
    unsigned int boff = (unsigned int)f << 2;       // 4B per lane

    float acc[4];
    {   // self term
        unsigned int w0 = *(const unsigned int*)(T8 + nodeC * 64u + boff);
        auto f0 = __builtin_amdgcn_cvt_pk_f32_fp8((int)w0, false);
        auto f1 = __builtin_amdgcn_cvt_pk_f32_fp8((int)w0, true);
        acc[0] = f0[0]; acc[1] = f0[1]; acc[2] = f1[0]; acc[3] = f1[1];
    }

    while (__any(e < end)) {                        // 8 edges/quarter/iter
        unsigned int s[8];
#pragma unroll
        for (int k = 0; k < 8; ++k) s[k] = (unsigned int)col[e + k];
#pragma unroll
        for (int k = 0; k < 8; ++k) {
            bool ok = (e + k) < end;
            unsigned int idx = ok ? min(s[k], (unsigned int)(N - 1)) : nodeC;
            unsigned int v = *(const unsigned int*)(T8 + idx * 64u + boff);
            v = ok ? v : 0u;
            fp8x4_acc(v, acc);
        }
        e += 8u;
    }

    float dv = dinv[nodeC];
    float4 bb = ((const float4*)b2)[f];
    float v0 = fmaf(dv, acc[0], bb.x);
    float v1 = fmaf(dv, acc[1], bb.y);
    float v2 = fmaf(dv, acc[2], bb.z);
    float v3 = fmaf(dv, acc[3], bb.w);
    float m = fmaxf(fmaxf(v0, v1), fmaxf(v2, v3));
#pragma unroll
    for (int off = 1; off < 16; off <<= 1) m = fmaxf(m, __shfl_xor(m, off));
    float sum = __expf(v0 - m) + __expf(v1 - m) + __expf(v2 - m) + __expf(v3 - m);
#pragma unroll
    for (int off = 1; off < 16; off <<= 1) sum += __shfl_xor(sum, off);
    float ls = m + logf(sum);
    if (act)
        ((float4*)OUT)[(size_t)node * 16 + f] =
            make_float4(v0 - ls, v1 - ls, v2 - ls, v3 - ls);
}

extern "C" void kernel_launch(void* const* d_in, const int* in_sizes, int n_in,
                              void* d_out, int out_size, void* d_ws, size_t ws_size,
                              hipStream_t stream) {
    const float* x   = (const float*)d_in[0];
    const int*   ei  = (const int*)d_in[1];   // int32 per harness contract
    const float* W1  = (const float*)d_in[2];
    const float* b1  = (const float*)d_in[3];
    const float* W2  = (const float*)d_in[4];
    const float* b2  = (const float*)d_in[5];
    float*       out = (float*)d_out;

    const int N = in_sizes[0] / 128;      // 100000
    const int E = in_sizes[1] / 2;        // 1600000
    const int* src = ei;
    const int* dst = ei + E;
    const int NB = (N + BSIZE - 1) >> BSHIFT;   // dst buckets (391 <= 512)
    const size_t CAPTOT = (size_t)NB << CAPSHIFT;

    // workspace layout
    char* ws = (char*)d_ws;
    size_t off = 0;
    auto alloc = [&](size_t bytes) { void* p = ws + off; off = (off + bytes + 255) & ~(size_t)255; return p; };
    unsigned int* deg    = (unsigned int*)alloc((size_t)N * 4);
    float*        dinv   = (float*)alloc((size_t)N * 4);
    unsigned int* cursor = (unsigned int*)alloc((size_t)N * 4);
    unsigned int* bf     = (unsigned int*)alloc(512 * 4);       // bucket_fill
    __half*       w1s    = (__half*)alloc(128 * 128 * 2);       // swizzled W1
    __half*       w2s    = (__half*)alloc(128 * 64 * 2);        // swizzled W2
    int*          col    = (int*)alloc(CAPTOT * 4 + 256);       // CAP-strided (+overrun pad)
    unsigned char* A     = (unsigned char*)alloc((size_t)N * 128); // T1'/T2' fp8
    __half*       B      = (__half*)alloc((size_t)N * 128 * 2);    // h fp16
    unsigned int* ebuf   = (unsigned int*)alloc(CAPTOT * 4);

    // 1. CSR build: partition (+swizzle in last block) -> per-bucket scatter
    hipMemsetAsync(bf, 0, 512 * 4, stream);
    int nPart = (E + P2_T * P2_I - 1) / (P2_T * P2_I);
    partition_kernel<<<nPart + 1, P2_T, 0, stream>>>(src, dst, bf, ebuf, W1, W2, w1s, w2s, E, NB);
    bucket_scatter2_kernel<<<NB, 256, 0, stream>>>(ebuf, bf, cursor, deg, dinv, col, N);
    // now cursor[i] == rowend(i); rowstart(i) = cursor[i] - deg[i]; dinv ready

    // 2. T1' = fp8(dinv * (x @ W1)) [MFMA];  h = relu(dinv*(pull) + b1)
    gemm1_mfma_kernel<<<(N + 63) / 64, 256, 0, stream>>>(x, w1s, dinv, A, N);
    pull_agg1_kernel<<<(N + 15) / 16, 256, 0, stream>>>(A, col, cursor, deg, dinv, b1, B, N);

    // 3. T2' = fp8(dinv * (h @ W2)) [MFMA];  out = logsoftmax(dinv*(pull) + b2)
    gemm2_mfma_kernel<<<(N + 63) / 64, 256, 0, stream>>>(B, w2s, dinv, A, N);
    pull_agg2_kernel<<<(N + 15) / 16, 256, 0, stream>>>(A, col, cursor, deg, dinv, b2, out, N);
}